// Round 1
// 707.532 us; speedup vs baseline: 1.2786x; 1.2786x over previous
//
#include <hip/hip_runtime.h>
#include <hip/hip_bf16.h>

typedef __hip_bfloat16 bf16;

#define D 128
#define NLEV 5
#define TE 8   // edges per tile
#define TN 8   // nodes per tile

// gate code -> t (enumerate index in CODES=[3,2,5,1,4]); index 0 unused
__constant__ int TMAP[6] = { -1, 3, 1, 0, 4, 2 };
// gate code -> func-aggregator index (FIDX={3:0,5:1,1:2,4:3}); codes 0,2 unused
__constant__ int FMAP[6] = { -1, 2, -1, 0, 3, 1 };

// dtype flag: 1 = float tensors stored as bf16, 0 = stored as float32
__device__ int g_flag;

__device__ __forceinline__ float sigm(float x) { return 1.0f / (1.0f + __expf(-x)); }

template <int ISB>
__device__ __forceinline__ float ld(const void* p, size_t i) {
    if (ISB) return __bfloat162float(((const bf16*)p)[i]);
    return ((const float*)p)[i];
}

// ---- dtype sniffer (unchanged) ----
__global__ void detect_dtype(const void* hs_init) {
    int t = threadIdx.x;
    float x = __bfloat162float(((const bf16*)hs_init)[2 * t]);
    float ax = fabsf(x);
    bool sane = (x == 0.0f) || (ax > 1e-4f && ax < 64.0f);
    unsigned long long m = __ballot(sane);
    if (t == 0) g_flag = (__popcll(m) >= 32) ? 1 : 0;
}

// ---- init: hs = PI ? hs_init : 0 ; hf = 0 ----
__global__ void init_state(const void* __restrict__ hs_init,
                           const int* __restrict__ gate,
                           float* __restrict__ hs, float* __restrict__ hf) {
    int v = blockIdx.x;
    int j = threadIdx.x;
    float val = 0.0f;
    if (gate[v] == 0) {
        size_t idx = (size_t)v * D + j;
        val = g_flag ? ld<1>(hs_init, idx) : ld<0>(hs_init, idx);
    }
    hs[(size_t)v * D + j] = val;
    hf[(size_t)v * D + j] = 0.0f;
}

// ================= bucketing: (level-1)*5 + t, levels 1..4 =================
__global__ void count_bins(const int* __restrict__ dstA, const int* __restrict__ gate,
                           const int* __restrict__ lev, int E, int N,
                           int* __restrict__ ecnt, int* __restrict__ ncnt) {
    __shared__ int lc[40];
    int tid = threadIdx.x;
    if (tid < 40) lc[tid] = 0;
    __syncthreads();
    int i = blockIdx.x * blockDim.x + tid;
    if (i < E) {
        int d = dstA[i]; int l = lev[d];
        if (l >= 1 && l < NLEV) atomicAdd(&lc[(l - 1) * 5 + TMAP[gate[d]]], 1);
    }
    if (i < N) {
        int l = lev[i];
        if (l >= 1 && l < NLEV && gate[i] >= 1) atomicAdd(&lc[20 + (l - 1) * 5 + TMAP[gate[i]]], 1);
    }
    __syncthreads();
    if (tid < 20 && lc[tid]) atomicAdd(&ecnt[tid], lc[tid]);
    if (tid >= 20 && tid < 40 && lc[tid]) atomicAdd(&ncnt[tid - 20], lc[tid]);
}

__global__ void scan_offsets(const int* __restrict__ ecnt, const int* __restrict__ ncnt,
                             int* __restrict__ eoff, int* __restrict__ noff) {
    if (threadIdx.x == 0 && blockIdx.x == 0) {
        int o = 0;
        for (int b = 0; b < 20; ++b) { eoff[b] = o; o += ((ecnt[b] + TE - 1) / TE) * TE; }
        eoff[20] = o;
        o = 0;
        for (int b = 0; b < 20; ++b) { noff[b] = o; o += ((ncnt[b] + TN - 1) / TN) * TN; }
        noff[20] = o;
    }
}

__global__ void fill_bins(const int* __restrict__ dstA, const int* __restrict__ gate,
                          const int* __restrict__ lev, int E, int N,
                          const int* __restrict__ eoff, const int* __restrict__ noff,
                          int* __restrict__ ecur, int* __restrict__ ncur,
                          int* __restrict__ elist, int* __restrict__ nlist) {
    __shared__ int ec[20], nc[20], eb[20], nb[20];
    int tid = threadIdx.x;
    if (tid < 20) { ec[tid] = 0; nc[tid] = 0; }
    __syncthreads();
    int i = blockIdx.x * blockDim.x + tid;
    int be = -1, re = 0, bn = -1, rn = 0;
    if (i < E) {
        int d = dstA[i]; int l = lev[d];
        if (l >= 1 && l < NLEV) { be = (l - 1) * 5 + TMAP[gate[d]]; re = atomicAdd(&ec[be], 1); }
    }
    if (i < N) {
        int l = lev[i];
        if (l >= 1 && l < NLEV && gate[i] >= 1) { bn = (l - 1) * 5 + TMAP[gate[i]]; rn = atomicAdd(&nc[bn], 1); }
    }
    __syncthreads();
    if (tid < 20) {
        eb[tid] = ec[tid] ? atomicAdd(&ecur[tid], ec[tid]) : 0;
        nb[tid] = nc[tid] ? atomicAdd(&ncur[tid], nc[tid]) : 0;
    }
    __syncthreads();
    if (be >= 0) elist[eoff[be] + eb[be] + re] = i;
    if (bn >= 0) nlist[noff[bn] + nb[bn] + rn] = i;
}

// ================= register-tiled 8-row GEMM slice =================
// C[8 rows][128 cols] += X[8][K] @ W[K][cols]; lane l owns cols {l, l+64}.
// Each weight element is reused across 8 rows; each LDS float4 x-read feeds 8 FMAs.
template <int ISB, int K>
__device__ __forceinline__ void mm8(
    const float* __restrict__ xs, int xstride,
    const void* __restrict__ W, size_t wofs, int wstride,
    const void* __restrict__ B, size_t bofs,
    int l, float (&out)[8][2]) {
    float b0 = ld<ISB>(B, bofs + l);
    float b1 = ld<ISB>(B, bofs + 64 + l);
#pragma unroll
    for (int r = 0; r < 8; ++r) { out[r][0] = b0; out[r][1] = b1; }
#pragma unroll 2
    for (int i = 0; i < K; i += 4) {
        size_t w0 = wofs + (size_t)i * wstride + l;
        float wa0 = ld<ISB>(W, w0);
        float wa1 = ld<ISB>(W, w0 + wstride);
        float wa2 = ld<ISB>(W, w0 + 2 * (size_t)wstride);
        float wa3 = ld<ISB>(W, w0 + 3 * (size_t)wstride);
        float wb0 = ld<ISB>(W, w0 + 64);
        float wb1 = ld<ISB>(W, w0 + wstride + 64);
        float wb2 = ld<ISB>(W, w0 + 2 * (size_t)wstride + 64);
        float wb3 = ld<ISB>(W, w0 + 3 * (size_t)wstride + 64);
#pragma unroll
        for (int r = 0; r < 8; ++r) {
            const float4 xv = *reinterpret_cast<const float4*>(xs + r * xstride + i);
            out[r][0] = fmaf(xv.w, wa3, fmaf(xv.z, wa2, fmaf(xv.y, wa1, fmaf(xv.x, wa0, out[r][0]))));
            out[r][1] = fmaf(xv.w, wb3, fmaf(xv.z, wb2, fmaf(xv.y, wb1, fmaf(xv.x, wb0, out[r][1]))));
        }
    }
}

// ================= edge tiles: 8 edges of one (level,code) bucket =================
template <int ISB>
__device__ void edge_tiles_body(
    const float* __restrict__ hs, const float* __restrict__ hf,
    const void* __restrict__ Ws1, const void* __restrict__ bs1,
    const void* __restrict__ Ws2, const void* __restrict__ bs2,
    const void* __restrict__ Wf1, const void* __restrict__ bf1,
    const void* __restrict__ Wf2, const void* __restrict__ bf2,
    const void* __restrict__ Wnf1, const void* __restrict__ bnf1,
    const void* __restrict__ Wnf2, const void* __restrict__ bnf2,
    const int* __restrict__ srcA, const int* __restrict__ dstA,
    const int* __restrict__ gate,
    const int* __restrict__ eoff, const int* __restrict__ elist,
    float* __restrict__ agg_s, float* __restrict__ agg_f, int level) {
    int lo = eoff[(level - 1) * 5];
    int hi = eoff[(level - 1) * 5 + 5];
    int base = lo + blockIdx.x * TE;
    if (base >= hi) return;
    int l = threadIdx.x;

    // buckets are padded to TE multiples -> slot 0 of every live tile is valid
    int e0 = elist[base];
    int c = gate[dstA[e0]];   // uniform over tile
    int t = TMAP[c];

    __shared__ int se[TE], de[TE];
    __shared__ __align__(16) float x[TE][2 * D];
    __shared__ __align__(16) float hid[TE][D];

    if (l < TE) {
        int e = elist[base + l];
        se[l] = (e < 0) ? -1 : srcA[e];
        de[l] = (e < 0) ? -1 : dstA[e];
    }
    __syncthreads();

    // gather [hs,hf] rows once per tile
#pragma unroll
    for (int r = 0; r < TE; ++r) {
        int s = se[r];
        float v0 = 0.f, v1 = 0.f, v2 = 0.f, v3 = 0.f;
        if (s >= 0) {
            size_t o = (size_t)s * D + l;
            v0 = hs[o]; v1 = hs[o + 64];
            v2 = hf[o]; v3 = hf[o + 64];
        }
        x[r][l] = v0; x[r][64 + l] = v1;
        x[r][D + l] = v2; x[r][D + 64 + l] = v3;
    }
    __syncthreads();

    float acc[8][2];

    // ---- structural: relu(hs @ Ws1[t]) @ Ws2[t] -> agg_s ----
    mm8<ISB, 128>(&x[0][0], 2 * D, Ws1, (size_t)t * D * D, D, bs1, (size_t)t * D, l, acc);
#pragma unroll
    for (int r = 0; r < TE; ++r) {
        hid[r][l] = fmaxf(acc[r][0], 0.f);
        hid[r][64 + l] = fmaxf(acc[r][1], 0.f);
    }
    __syncthreads();
    mm8<ISB, 128>(&hid[0][0], D, Ws2, (size_t)t * D * D, D, bs2, (size_t)t * D, l, acc);
#pragma unroll
    for (int r = 0; r < TE; ++r) {
        int d = de[r];
        if (d >= 0) {
            atomicAdd(&agg_s[(size_t)d * D + l], acc[r][0]);
            atomicAdd(&agg_s[(size_t)d * D + 64 + l], acc[r][1]);
        }
    }
    __syncthreads();   // hid about to be overwritten

    // ---- functional ----
    if (c == 2) {  // NOT: relu(hf @ Wnf1) @ Wnf2
        mm8<ISB, 128>(&x[0][D], 2 * D, Wnf1, 0, D, bnf1, 0, l, acc);
    } else {       // AND/XOR/MAJ/OR: relu([hs,hf] @ Wf1[fi]) @ Wf2[fi]
        int fi = FMAP[c];
        mm8<ISB, 256>(&x[0][0], 2 * D, Wf1, (size_t)fi * 2 * D * D, D, bf1, (size_t)fi * D, l, acc);
    }
#pragma unroll
    for (int r = 0; r < TE; ++r) {
        hid[r][l] = fmaxf(acc[r][0], 0.f);
        hid[r][64 + l] = fmaxf(acc[r][1], 0.f);
    }
    __syncthreads();
    if (c == 2) {
        mm8<ISB, 128>(&hid[0][0], D, Wnf2, 0, D, bnf2, 0, l, acc);
    } else {
        int fi = FMAP[c];
        mm8<ISB, 128>(&hid[0][0], D, Wf2, (size_t)fi * D * D, D, bf2, (size_t)fi * D, l, acc);
    }
#pragma unroll
    for (int r = 0; r < TE; ++r) {
        int d = de[r];
        if (d >= 0) {
            atomicAdd(&agg_f[(size_t)d * D + l], acc[r][0]);
            atomicAdd(&agg_f[(size_t)d * D + 64 + l], acc[r][1]);
        }
    }
}

__global__ __launch_bounds__(64) void edge_tiles(
    const float* hs, const float* hf,
    const void* Ws1, const void* bs1, const void* Ws2, const void* bs2,
    const void* Wf1, const void* bf1, const void* Wf2, const void* bf2,
    const void* Wnf1, const void* bnf1, const void* Wnf2, const void* bnf2,
    const int* srcA, const int* dstA, const int* gate,
    const int* eoff, const int* elist,
    float* agg_s, float* agg_f, int level) {
    if (g_flag)
        edge_tiles_body<1>(hs, hf, Ws1, bs1, Ws2, bs2, Wf1, bf1, Wf2, bf2,
                           Wnf1, bnf1, Wnf2, bnf2, srcA, dstA, gate, eoff, elist,
                           agg_s, agg_f, level);
    else
        edge_tiles_body<0>(hs, hf, Ws1, bs1, Ws2, bs2, Wf1, bf1, Wf2, bf2,
                           Wnf1, bnf1, Wnf2, bnf2, srcA, dstA, gate, eoff, elist,
                           agg_s, agg_f, level);
}

// ================= node tiles: 8 nodes, batched simplified GRU (h==0) =================
template <int ISB>
__device__ __forceinline__ void gru_pass(
    float* __restrict__ h, const float* __restrict__ agg,
    const void* __restrict__ wih, const void* __restrict__ bih,
    const void* __restrict__ bhh,
    int t, int l, const int* __restrict__ nd, float (*xa)[D]) {
#pragma unroll
    for (int r = 0; r < TN; ++r) {
        int v = nd[r];
        float a0 = 0.f, a1 = 0.f;
        if (v >= 0) {
            a0 = agg[(size_t)v * D + l];
            a1 = agg[(size_t)v * D + 64 + l];
        }
        xa[r][l] = a0; xa[r][64 + l] = a1;
    }
    __syncthreads();
    size_t wof = (size_t)t * D * 3 * D;
    size_t bof = (size_t)t * 3 * D;
    float accR[8][2], accZ[8][2], accN[8][2];
    mm8<ISB, 128>(&xa[0][0], D, wih, wof,          3 * D, bih, bof,          l, accR);
    mm8<ISB, 128>(&xa[0][0], D, wih, wof + D,      3 * D, bih, bof + D,      l, accZ);
    mm8<ISB, 128>(&xa[0][0], D, wih, wof + 2 * D,  3 * D, bih, bof + 2 * D,  l, accN);
    float hr0 = ld<ISB>(bhh, bof + l),         hr1 = ld<ISB>(bhh, bof + 64 + l);
    float hz0 = ld<ISB>(bhh, bof + D + l),     hz1 = ld<ISB>(bhh, bof + D + 64 + l);
    float hn0 = ld<ISB>(bhh, bof + 2 * D + l), hn1 = ld<ISB>(bhh, bof + 2 * D + 64 + l);
#pragma unroll
    for (int r = 0; r < TN; ++r) {
        int v = nd[r];
        if (v < 0) continue;
        float rr0 = sigm(accR[r][0] + hr0);
        float z0 = sigm(accZ[r][0] + hz0);
        float n0 = tanhf(accN[r][0] + rr0 * hn0);
        float rr1 = sigm(accR[r][1] + hr1);
        float z1 = sigm(accZ[r][1] + hz1);
        float n1 = tanhf(accN[r][1] + rr1 * hn1);
        h[(size_t)v * D + l] = (1.f - z0) * n0;
        h[(size_t)v * D + 64 + l] = (1.f - z1) * n1;
    }
    __syncthreads();   // xa reused by next pass
}

template <int ISB>
__device__ void node_tiles_body(
    float* __restrict__ hs, float* __restrict__ hf,
    const float* __restrict__ agg_s, const float* __restrict__ agg_f,
    const void* __restrict__ Gs_wih, const void* __restrict__ Gs_bih, const void* __restrict__ Gs_bhh,
    const void* __restrict__ Gf_wih, const void* __restrict__ Gf_bih, const void* __restrict__ Gf_bhh,
    const int* __restrict__ gate,
    const int* __restrict__ noff, const int* __restrict__ nlist, int level) {
    int lo = noff[(level - 1) * 5];
    int hi = noff[(level - 1) * 5 + 5];
    int base = lo + blockIdx.x * TN;
    if (base >= hi) return;
    int l = threadIdx.x;
    int t = TMAP[gate[nlist[base]]];

    __shared__ int nd[TN];
    __shared__ __align__(16) float xa[TN][D];

    if (l < TN) nd[l] = nlist[base + l];
    __syncthreads();

    gru_pass<ISB>(hs, agg_s, Gs_wih, Gs_bih, Gs_bhh, t, l, nd, xa);
    gru_pass<ISB>(hf, agg_f, Gf_wih, Gf_bih, Gf_bhh, t, l, nd, xa);
}

__global__ __launch_bounds__(64) void node_tiles(
    float* hs, float* hf, const float* agg_s, const float* agg_f,
    const void* Gs_wih, const void* Gs_bih, const void* Gs_bhh,
    const void* Gf_wih, const void* Gf_bih, const void* Gf_bhh,
    const int* gate, const int* noff, const int* nlist, int level) {
    if (g_flag)
        node_tiles_body<1>(hs, hf, agg_s, agg_f, Gs_wih, Gs_bih, Gs_bhh,
                           Gf_wih, Gf_bih, Gf_bhh, gate, noff, nlist, level);
    else
        node_tiles_body<0>(hs, hf, agg_s, agg_f, Gs_wih, Gs_bih, Gs_bhh,
                           Gf_wih, Gf_bih, Gf_bhh, gate, noff, nlist, level);
}

// ---------------- writeout ----------------
__global__ void writeout(const float* __restrict__ hs, const float* __restrict__ hf,
                         void* __restrict__ out, int ND) {
    int i = blockIdx.x * blockDim.x + threadIdx.x;
    if (i >= ND) return;
    if (g_flag) {
        ((bf16*)out)[i] = __float2bfloat16(hs[i]);
        ((bf16*)out)[ND + i] = __float2bfloat16(hf[i]);
    } else {
        ((float*)out)[i] = hs[i];
        ((float*)out)[ND + i] = hf[i];
    }
}

extern "C" void kernel_launch(void* const* d_in, const int* in_sizes, int n_in,
                              void* d_out, int out_size, void* d_ws, size_t ws_size,
                              hipStream_t stream) {
    const void* hs_init = d_in[0];
    const void* Ws1 = d_in[1];
    const void* bs1 = d_in[2];
    const void* Ws2 = d_in[3];
    const void* bs2 = d_in[4];
    const void* Wf1 = d_in[5];
    const void* bf1 = d_in[6];
    const void* Wf2 = d_in[7];
    const void* bf2 = d_in[8];
    const void* Wnf1 = d_in[9];
    const void* bnf1 = d_in[10];
    const void* Wnf2 = d_in[11];
    const void* bnf2 = d_in[12];
    const void* Gs_wih = d_in[13];
    // d_in[14] = Gs_whh (unused: h==0 at GRU time)
    const void* Gs_bih = d_in[15];
    const void* Gs_bhh = d_in[16];
    const void* Gf_wih = d_in[17];
    // d_in[18] = Gf_whh (unused)
    const void* Gf_bih = d_in[19];
    const void* Gf_bhh = d_in[20];
    const int* edge_index = (const int*)d_in[21];
    const int* gate = (const int*)d_in[22];
    const int* lev = (const int*)d_in[23];

    int E = in_sizes[21] / 2;
    int N = in_sizes[22];
    int ND = N * D;

    float* hs = (float*)d_ws;
    float* hf = hs + ND;
    float* agg_s = hf + ND;
    float* agg_f = agg_s + ND;
    int* meta = (int*)(agg_f + ND);
    int* ecnt = meta;           // 20
    int* ncnt = ecnt + 20;      // 20
    int* ecur = ncnt + 20;      // 20
    int* ncur = ecur + 20;      // 20
    int* eoff = ncur + 20;      // 21
    int* noff = eoff + 21;      // 21
    int* elist = noff + 21;     // E + 20*TE
    int* nlist = elist + (E + 20 * TE);  // N + 20*TN

    const int* srcA = edge_index;
    const int* dstA = edge_index + E;

    detect_dtype<<<1, 64, 0, stream>>>(hs_init);
    hipMemsetAsync(agg_s, 0, (size_t)2 * ND * sizeof(float), stream);
    hipMemsetAsync(meta, 0, 80 * sizeof(int), stream);
    hipMemsetAsync(elist, 0xFF, (size_t)(E + 20 * TE + N + 20 * TN) * sizeof(int), stream);
    init_state<<<N, D, 0, stream>>>(hs_init, gate, hs, hf);

    int mx = (E > N) ? E : N;
    count_bins<<<(mx + 255) / 256, 256, 0, stream>>>(dstA, gate, lev, E, N, ecnt, ncnt);
    scan_offsets<<<1, 64, 0, stream>>>(ecnt, ncnt, eoff, noff);
    fill_bins<<<(mx + 255) / 256, 256, 0, stream>>>(dstA, gate, lev, E, N,
                                                    eoff, noff, ecur, ncur, elist, nlist);

    int gridE = (E + TE - 1) / TE + 6;
    int gridN = (N + TN - 1) / TN + 6;
    for (int level = 1; level < NLEV; ++level) {
        edge_tiles<<<gridE, 64, 0, stream>>>(hs, hf, Ws1, bs1, Ws2, bs2,
                                             Wf1, bf1, Wf2, bf2,
                                             Wnf1, bnf1, Wnf2, bnf2,
                                             srcA, dstA, gate, eoff, elist,
                                             agg_s, agg_f, level);
        node_tiles<<<gridN, 64, 0, stream>>>(hs, hf, agg_s, agg_f,
                                             Gs_wih, Gs_bih, Gs_bhh,
                                             Gf_wih, Gf_bih, Gf_bhh,
                                             gate, noff, nlist, level);
    }

    writeout<<<(ND + 255) / 256, 256, 0, stream>>>(hs, hf, d_out, ND);
}

// Round 2
// 503.716 us; speedup vs baseline: 1.7960x; 1.4046x over previous
//
#include <hip/hip_runtime.h>
#include <hip/hip_bf16.h>

typedef __hip_bfloat16 bf16;

#define D 128
#define NLEV 5
#define TE 8   // edges per tile
#define TN 8   // nodes per tile

// gate code -> t (enumerate index in CODES=[3,2,5,1,4]); index 0 unused
__constant__ int TMAP[6] = { -1, 3, 1, 0, 4, 2 };
// gate code -> func-aggregator index (FIDX={3:0,5:1,1:2,4:3}); codes 0,2 unused
__constant__ int FMAP[6] = { -1, 2, -1, 0, 3, 1 };

// dtype flag: 1 = float tensors stored as bf16, 0 = stored as float32
__device__ int g_flag;

__device__ __forceinline__ float sigm(float x) { return 1.0f / (1.0f + __expf(-x)); }

template <int ISB>
__device__ __forceinline__ float ld(const void* p, size_t i) {
    if (ISB) return __bfloat162float(((const bf16*)p)[i]);
    return ((const float*)p)[i];
}

// load two adjacent elements (i must be even)
template <int ISB>
__device__ __forceinline__ float2 ld2(const void* p, size_t i) {
    if (ISB) {
        __hip_bfloat162 v = *(const __hip_bfloat162*)((const bf16*)p + i);
        return make_float2(__bfloat162float(v.x), __bfloat162float(v.y));
    }
    return *(const float2*)((const float*)p + i);
}

// ---- dtype sniffer ----
__global__ void detect_dtype(const void* hs_init) {
    int t = threadIdx.x;
    float x = __bfloat162float(((const bf16*)hs_init)[2 * t]);
    float ax = fabsf(x);
    bool sane = (x == 0.0f) || (ax > 1e-4f && ax < 64.0f);
    unsigned long long m = __ballot(sane);
    if (t == 0) g_flag = (__popcll(m) >= 32) ? 1 : 0;
}

// ---- init: hs = PI ? hs_init : 0 ; hf = 0 ----
__global__ void init_state(const void* __restrict__ hs_init,
                           const int* __restrict__ gate,
                           float* __restrict__ hs, float* __restrict__ hf) {
    int v = blockIdx.x;
    int j = threadIdx.x;
    float val = 0.0f;
    if (gate[v] == 0) {
        size_t idx = (size_t)v * D + j;
        val = g_flag ? ld<1>(hs_init, idx) : ld<0>(hs_init, idx);
    }
    hs[(size_t)v * D + j] = val;
    hf[(size_t)v * D + j] = 0.0f;
}

// ================= bucketing: (level-1)*5 + t, levels 1..4 =================
__global__ void count_bins(const int* __restrict__ dstA, const int* __restrict__ gate,
                           const int* __restrict__ lev, int E, int N,
                           int* __restrict__ ecnt, int* __restrict__ ncnt) {
    __shared__ int lc[40];
    int tid = threadIdx.x;
    if (tid < 40) lc[tid] = 0;
    __syncthreads();
    int i = blockIdx.x * blockDim.x + tid;
    if (i < E) {
        int d = dstA[i]; int l = lev[d];
        if (l >= 1 && l < NLEV) atomicAdd(&lc[(l - 1) * 5 + TMAP[gate[d]]], 1);
    }
    if (i < N) {
        int l = lev[i];
        if (l >= 1 && l < NLEV && gate[i] >= 1) atomicAdd(&lc[20 + (l - 1) * 5 + TMAP[gate[i]]], 1);
    }
    __syncthreads();
    if (tid < 20 && lc[tid]) atomicAdd(&ecnt[tid], lc[tid]);
    if (tid >= 20 && tid < 40 && lc[tid]) atomicAdd(&ncnt[tid - 20], lc[tid]);
}

__global__ void scan_offsets(const int* __restrict__ ecnt, const int* __restrict__ ncnt,
                             int* __restrict__ eoff, int* __restrict__ noff) {
    if (threadIdx.x == 0 && blockIdx.x == 0) {
        int o = 0;
        for (int b = 0; b < 20; ++b) { eoff[b] = o; o += ((ecnt[b] + TE - 1) / TE) * TE; }
        eoff[20] = o;
        o = 0;
        for (int b = 0; b < 20; ++b) { noff[b] = o; o += ((ncnt[b] + TN - 1) / TN) * TN; }
        noff[20] = o;
    }
}

__global__ void fill_bins(const int* __restrict__ dstA, const int* __restrict__ gate,
                          const int* __restrict__ lev, int E, int N,
                          const int* __restrict__ eoff, const int* __restrict__ noff,
                          int* __restrict__ ecur, int* __restrict__ ncur,
                          int* __restrict__ elist, int* __restrict__ nlist) {
    __shared__ int ec[20], nc[20], eb[20], nb[20];
    int tid = threadIdx.x;
    if (tid < 20) { ec[tid] = 0; nc[tid] = 0; }
    __syncthreads();
    int i = blockIdx.x * blockDim.x + tid;
    int be = -1, re = 0, bn = -1, rn = 0;
    if (i < E) {
        int d = dstA[i]; int l = lev[d];
        if (l >= 1 && l < NLEV) { be = (l - 1) * 5 + TMAP[gate[d]]; re = atomicAdd(&ec[be], 1); }
    }
    if (i < N) {
        int l = lev[i];
        if (l >= 1 && l < NLEV && gate[i] >= 1) { bn = (l - 1) * 5 + TMAP[gate[i]]; rn = atomicAdd(&nc[bn], 1); }
    }
    __syncthreads();
    if (tid < 20) {
        eb[tid] = ec[tid] ? atomicAdd(&ecur[tid], ec[tid]) : 0;
        nb[tid] = nc[tid] ? atomicAdd(&ncur[tid], nc[tid]) : 0;
    }
    __syncthreads();
    if (be >= 0) elist[eoff[be] + eb[be] + re] = i;
    if (bn >= 0) nlist[noff[bn] + nb[bn] + rn] = i;
}

// ================= register-tiled R-row GEMM slice =================
// out[R][2] = X[R][K] @ W[K][cols] at cols (c0, c0+1), + optional bias.
// Adjacent-col trick: one float2/bf16x2 load yields both columns' weights.
template <int ISB, int K, int R>
__device__ __forceinline__ void mmT(
    const float* __restrict__ xs, int xstride,
    const void* __restrict__ W, size_t wofs, int wstride,
    const void* __restrict__ B, size_t bofs,
    int c0, float (&out)[R][2]) {
    float2 b = B ? ld2<ISB>(B, bofs + c0) : make_float2(0.f, 0.f);
#pragma unroll
    for (int r = 0; r < R; ++r) { out[r][0] = b.x; out[r][1] = b.y; }
#pragma unroll 2
    for (int i = 0; i < K; i += 4) {
        size_t w0 = wofs + (size_t)i * wstride + c0;
        float2 wa = ld2<ISB>(W, w0);
        float2 wb = ld2<ISB>(W, w0 + wstride);
        float2 wc = ld2<ISB>(W, w0 + 2 * (size_t)wstride);
        float2 wd = ld2<ISB>(W, w0 + 3 * (size_t)wstride);
#pragma unroll
        for (int r = 0; r < R; ++r) {
            const float4 xv = *reinterpret_cast<const float4*>(xs + r * xstride + i);
            out[r][0] = fmaf(xv.w, wd.x, fmaf(xv.z, wc.x, fmaf(xv.y, wb.x, fmaf(xv.x, wa.x, out[r][0]))));
            out[r][1] = fmaf(xv.w, wd.y, fmaf(xv.z, wc.y, fmaf(xv.y, wb.y, fmaf(xv.x, wa.y, out[r][1]))));
        }
    }
}

// ================= edge tiles: blockIdx.y = 0 structural / 1 functional =================
template <int ISB>
__device__ void edge_tiles_body(
    const float* __restrict__ hs, const float* __restrict__ hf,
    const void* __restrict__ Ws1, const void* __restrict__ bs1,
    const void* __restrict__ Ws2, const void* __restrict__ bs2,
    const void* __restrict__ Wf1, const void* __restrict__ bf1,
    const void* __restrict__ Wf2, const void* __restrict__ bf2,
    const void* __restrict__ Wnf1, const void* __restrict__ bnf1,
    const void* __restrict__ Wnf2, const void* __restrict__ bnf2,
    const int* __restrict__ srcA, const int* __restrict__ dstA,
    const int* __restrict__ gate,
    const int* __restrict__ eoff, const int* __restrict__ elist,
    float* __restrict__ agg_s, float* __restrict__ agg_f, int level) {
    int lo = eoff[(level - 1) * 5];
    int hi = eoff[(level - 1) * 5 + 5];
    int base = lo + blockIdx.x * TE;
    if (base >= hi) return;
    int l = threadIdx.x;
    int c0 = 2 * l;

    int e0 = elist[base];
    int c = gate[dstA[e0]];   // uniform over tile (buckets padded to TE)
    int t = TMAP[c];

    __shared__ int se[TE], de[TE];
    __shared__ __align__(16) float x[TE][2 * D];
    __shared__ __align__(16) float hid[TE][D];

    if (l < TE) {
        int e = elist[base + l];
        se[l] = (e < 0) ? -1 : srcA[e];
        de[l] = (e < 0) ? -1 : dstA[e];
    }
    __syncthreads();

    float acc[TE][2];

    if (blockIdx.y == 0) {
        // ---- structural: relu(hs @ Ws1[t]) @ Ws2[t] -> agg_s ----
#pragma unroll
        for (int r = 0; r < TE; ++r) {
            int s = se[r];
            float2 v = (s >= 0) ? *(const float2*)&hs[(size_t)s * D + c0] : make_float2(0.f, 0.f);
            *(float2*)&x[r][c0] = v;
        }
        __syncthreads();
        mmT<ISB, 128, TE>(&x[0][0], 2 * D, Ws1, (size_t)t * D * D, D, bs1, (size_t)t * D, c0, acc);
#pragma unroll
        for (int r = 0; r < TE; ++r) {
            hid[r][c0] = fmaxf(acc[r][0], 0.f);
            hid[r][c0 + 1] = fmaxf(acc[r][1], 0.f);
        }
        __syncthreads();
        mmT<ISB, 128, TE>(&hid[0][0], D, Ws2, (size_t)t * D * D, D, bs2, (size_t)t * D, c0, acc);
#pragma unroll
        for (int r = 0; r < TE; ++r) {
            int d = de[r];
            if (d >= 0) {
                atomicAdd(&agg_s[(size_t)d * D + c0], acc[r][0]);
                atomicAdd(&agg_s[(size_t)d * D + c0 + 1], acc[r][1]);
            }
        }
    } else {
        // ---- functional ----
        if (c == 2) {  // NOT: relu(hf @ Wnf1) @ Wnf2
#pragma unroll
            for (int r = 0; r < TE; ++r) {
                int s = se[r];
                float2 v = (s >= 0) ? *(const float2*)&hf[(size_t)s * D + c0] : make_float2(0.f, 0.f);
                *(float2*)&x[r][c0] = v;
            }
            __syncthreads();
            mmT<ISB, 128, TE>(&x[0][0], 2 * D, Wnf1, 0, D, bnf1, 0, c0, acc);
        } else {       // relu([hs,hf] @ Wf1[fi]) @ Wf2[fi]
#pragma unroll
            for (int r = 0; r < TE; ++r) {
                int s = se[r];
                float2 v0 = make_float2(0.f, 0.f), v1 = v0;
                if (s >= 0) {
                    v0 = *(const float2*)&hs[(size_t)s * D + c0];
                    v1 = *(const float2*)&hf[(size_t)s * D + c0];
                }
                *(float2*)&x[r][c0] = v0;
                *(float2*)&x[r][D + c0] = v1;
            }
            __syncthreads();
            int fi = FMAP[c];
            mmT<ISB, 256, TE>(&x[0][0], 2 * D, Wf1, (size_t)fi * 2 * D * D, D, bf1, (size_t)fi * D, c0, acc);
        }
#pragma unroll
        for (int r = 0; r < TE; ++r) {
            hid[r][c0] = fmaxf(acc[r][0], 0.f);
            hid[r][c0 + 1] = fmaxf(acc[r][1], 0.f);
        }
        __syncthreads();
        if (c == 2) {
            mmT<ISB, 128, TE>(&hid[0][0], D, Wnf2, 0, D, bnf2, 0, c0, acc);
        } else {
            int fi = FMAP[c];
            mmT<ISB, 128, TE>(&hid[0][0], D, Wf2, (size_t)fi * D * D, D, bf2, (size_t)fi * D, c0, acc);
        }
#pragma unroll
        for (int r = 0; r < TE; ++r) {
            int d = de[r];
            if (d >= 0) {
                atomicAdd(&agg_f[(size_t)d * D + c0], acc[r][0]);
                atomicAdd(&agg_f[(size_t)d * D + c0 + 1], acc[r][1]);
            }
        }
    }
}

__global__ __launch_bounds__(64) void edge_tiles(
    const float* hs, const float* hf,
    const void* Ws1, const void* bs1, const void* Ws2, const void* bs2,
    const void* Wf1, const void* bf1, const void* Wf2, const void* bf2,
    const void* Wnf1, const void* bnf1, const void* Wnf2, const void* bnf2,
    const int* srcA, const int* dstA, const int* gate,
    const int* eoff, const int* elist,
    float* agg_s, float* agg_f, int level) {
    if (g_flag)
        edge_tiles_body<1>(hs, hf, Ws1, bs1, Ws2, bs2, Wf1, bf1, Wf2, bf2,
                           Wnf1, bnf1, Wnf2, bnf2, srcA, dstA, gate, eoff, elist,
                           agg_s, agg_f, level);
    else
        edge_tiles_body<0>(hs, hf, Ws1, bs1, Ws2, bs2, Wf1, bf1, Wf2, bf2,
                           Wnf1, bnf1, Wnf2, bnf2, srcA, dstA, gate, eoff, elist,
                           agg_s, agg_f, level);
}

// ================= node GEMM: gi partials, split (pass, colgroup, k-half) =================
// blockIdx.y = p*6 + g*2 + h :  p in {hs,hf}, g in {r,z,n}, h = K-half
template <int ISB>
__device__ void node_gemm_body(
    const float* __restrict__ agg_s, const float* __restrict__ agg_f,
    const void* __restrict__ Gs_wih, const void* __restrict__ Gf_wih,
    const int* __restrict__ gate,
    const int* __restrict__ noff, const int* __restrict__ nlist,
    float* __restrict__ gtmp, int level, int cap) {
    int lo = noff[(level - 1) * 5];
    int hi = noff[(level - 1) * 5 + 5];
    int base = lo + blockIdx.x * TN;
    if (base >= hi) return;
    int y = blockIdx.y;
    int p = y / 6, gh = y % 6;
    int g = gh / 2, h = gh % 2;
    int l = threadIdx.x;
    int c0 = 2 * l;
    int t = TMAP[gate[nlist[base]]];

    const float* agg = p ? agg_f : agg_s;
    const void* wih = p ? Gf_wih : Gs_wih;

    __shared__ int nd[TN];
    __shared__ __align__(16) float x[TN][64];
    if (l < TN) nd[l] = nlist[base + l];
    __syncthreads();
#pragma unroll
    for (int r = 0; r < TN; ++r) {
        int v = nd[r];
        x[r][l] = (v >= 0) ? agg[(size_t)v * D + h * 64 + l] : 0.f;
    }
    __syncthreads();

    float acc[TN][2];
    size_t wofs = (size_t)t * D * 3 * D + (size_t)(h * 64) * 3 * D;
    mmT<ISB, 64, TN>(&x[0][0], 64, wih, wofs, 3 * D, (const void*)0, 0, g * 128 + c0, acc);

    size_t tb = (((size_t)(p * 2 + h)) * cap + (base - lo)) * 384 + g * 128 + c0;
#pragma unroll
    for (int r = 0; r < TN; ++r) {
        *(float2*)&gtmp[tb + (size_t)r * 384] = make_float2(acc[r][0], acc[r][1]);
    }
}

__global__ __launch_bounds__(64) void node_gemm(
    const float* agg_s, const float* agg_f,
    const void* Gs_wih, const void* Gf_wih,
    const int* gate, const int* noff, const int* nlist,
    float* gtmp, int level, int cap) {
    if (g_flag)
        node_gemm_body<1>(agg_s, agg_f, Gs_wih, Gf_wih, gate, noff, nlist, gtmp, level, cap);
    else
        node_gemm_body<0>(agg_s, agg_f, Gs_wih, Gf_wih, gate, noff, nlist, gtmp, level, cap);
}

// ================= node epilogue: sum K-halves + biases + GRU nonlinearity =================
template <int ISB>
__device__ void node_epi_body(
    float* __restrict__ hs, float* __restrict__ hf,
    const float* __restrict__ gtmp,
    const void* __restrict__ Gs_bih, const void* __restrict__ Gs_bhh,
    const void* __restrict__ Gf_bih, const void* __restrict__ Gf_bhh,
    const int* __restrict__ gate,
    const int* __restrict__ noff, const int* __restrict__ nlist,
    int level, int cap) {
    int lo = noff[(level - 1) * 5];
    int hi = noff[(level - 1) * 5 + 5];
    int base = lo + blockIdx.x * TN;
    if (base >= hi) return;
    int j = threadIdx.x;  // 0..127
    int t = TMAP[gate[nlist[base]]];

#pragma unroll
    for (int p = 0; p < 2; ++p) {
        const void* bih = p ? Gf_bih : Gs_bih;
        const void* bhh = p ? Gf_bhh : Gs_bhh;
        float br = ld<ISB>(bih, (size_t)t * 384 + j);
        float bz = ld<ISB>(bih, (size_t)t * 384 + 128 + j);
        float bn = ld<ISB>(bih, (size_t)t * 384 + 256 + j);
        float hr = ld<ISB>(bhh, (size_t)t * 384 + j);
        float hz = ld<ISB>(bhh, (size_t)t * 384 + 128 + j);
        float hn = ld<ISB>(bhh, (size_t)t * 384 + 256 + j);
        float* hout = p ? hf : hs;
        const float* g0 = gtmp + ((size_t)(p * 2 + 0)) * cap * 384;
        const float* g1 = gtmp + ((size_t)(p * 2 + 1)) * cap * 384;
#pragma unroll
        for (int r = 0; r < TN; ++r) {
            int v = nlist[base + r];
            if (v < 0) continue;
            size_t pos = (size_t)(base - lo + r) * 384;
            float gr = g0[pos + j] + g1[pos + j];
            float gz = g0[pos + 128 + j] + g1[pos + 128 + j];
            float gn = g0[pos + 256 + j] + g1[pos + 256 + j];
            float rr = sigm(gr + br + hr);
            float z = sigm(gz + bz + hz);
            float n = tanhf(gn + bn + rr * hn);
            hout[(size_t)v * D + j] = (1.f - z) * n;
        }
    }
}

__global__ __launch_bounds__(128) void node_epi(
    float* hs, float* hf, const float* gtmp,
    const void* Gs_bih, const void* Gs_bhh,
    const void* Gf_bih, const void* Gf_bhh,
    const int* gate, const int* noff, const int* nlist, int level, int cap) {
    if (g_flag)
        node_epi_body<1>(hs, hf, gtmp, Gs_bih, Gs_bhh, Gf_bih, Gf_bhh,
                         gate, noff, nlist, level, cap);
    else
        node_epi_body<0>(hs, hf, gtmp, Gs_bih, Gs_bhh, Gf_bih, Gf_bhh,
                         gate, noff, nlist, level, cap);
}

// ---------------- writeout ----------------
__global__ void writeout(const float* __restrict__ hs, const float* __restrict__ hf,
                         void* __restrict__ out, int ND) {
    int i = blockIdx.x * blockDim.x + threadIdx.x;
    if (i >= ND) return;
    if (g_flag) {
        ((bf16*)out)[i] = __float2bfloat16(hs[i]);
        ((bf16*)out)[ND + i] = __float2bfloat16(hf[i]);
    } else {
        ((float*)out)[i] = hs[i];
        ((float*)out)[ND + i] = hf[i];
    }
}

extern "C" void kernel_launch(void* const* d_in, const int* in_sizes, int n_in,
                              void* d_out, int out_size, void* d_ws, size_t ws_size,
                              hipStream_t stream) {
    const void* hs_init = d_in[0];
    const void* Ws1 = d_in[1];
    const void* bs1 = d_in[2];
    const void* Ws2 = d_in[3];
    const void* bs2 = d_in[4];
    const void* Wf1 = d_in[5];
    const void* bf1 = d_in[6];
    const void* Wf2 = d_in[7];
    const void* bf2 = d_in[8];
    const void* Wnf1 = d_in[9];
    const void* bnf1 = d_in[10];
    const void* Wnf2 = d_in[11];
    const void* bnf2 = d_in[12];
    const void* Gs_wih = d_in[13];
    // d_in[14] = Gs_whh (unused: h==0 at GRU time)
    const void* Gs_bih = d_in[15];
    const void* Gs_bhh = d_in[16];
    const void* Gf_wih = d_in[17];
    // d_in[18] = Gf_whh (unused)
    const void* Gf_bih = d_in[19];
    const void* Gf_bhh = d_in[20];
    const int* edge_index = (const int*)d_in[21];
    const int* gate = (const int*)d_in[22];
    const int* lev = (const int*)d_in[23];

    int E = in_sizes[21] / 2;
    int N = in_sizes[22];
    int ND = N * D;
    // per-level node window bound: levels are ~N/NLEV nodes + bucket padding
    int cap = ((N / NLEV + 5 * TN + 64) + TN - 1) / TN * TN;

    float* hs = (float*)d_ws;
    float* hf = hs + ND;
    float* agg_s = hf + ND;
    float* agg_f = agg_s + ND;
    float* gtmp = agg_f + ND;                  // 4 * cap * 384 floats
    int* meta = (int*)(gtmp + (size_t)4 * cap * 384);
    int* ecnt = meta;           // 20
    int* ncnt = ecnt + 20;      // 20
    int* ecur = ncnt + 20;      // 20
    int* ncur = ecur + 20;      // 20
    int* eoff = ncur + 20;      // 21
    int* noff = eoff + 21;      // 21
    int* elist = noff + 21;     // E + 20*TE
    int* nlist = elist + (E + 20 * TE);  // N + 20*TN

    const int* srcA = edge_index;
    const int* dstA = edge_index + E;

    detect_dtype<<<1, 64, 0, stream>>>(hs_init);
    hipMemsetAsync(agg_s, 0, (size_t)2 * ND * sizeof(float), stream);
    hipMemsetAsync(meta, 0, 80 * sizeof(int), stream);
    hipMemsetAsync(elist, 0xFF, (size_t)(E + 20 * TE + N + 20 * TN) * sizeof(int), stream);
    init_state<<<N, D, 0, stream>>>(hs_init, gate, hs, hf);

    int mx = (E > N) ? E : N;
    count_bins<<<(mx + 255) / 256, 256, 0, stream>>>(dstA, gate, lev, E, N, ecnt, ncnt);
    scan_offsets<<<1, 64, 0, stream>>>(ecnt, ncnt, eoff, noff);
    fill_bins<<<(mx + 255) / 256, 256, 0, stream>>>(dstA, gate, lev, E, N,
                                                    eoff, noff, ecur, ncur, elist, nlist);

    int gridE = (E + 20 * TE) / TE + 1;
    int gridNcap = cap / TN;
    for (int level = 1; level < NLEV; ++level) {
        edge_tiles<<<dim3(gridE, 2), 64, 0, stream>>>(hs, hf, Ws1, bs1, Ws2, bs2,
                                                      Wf1, bf1, Wf2, bf2,
                                                      Wnf1, bnf1, Wnf2, bnf2,
                                                      srcA, dstA, gate, eoff, elist,
                                                      agg_s, agg_f, level);
        node_gemm<<<dim3(gridNcap, 12), 64, 0, stream>>>(agg_s, agg_f, Gs_wih, Gf_wih,
                                                         gate, noff, nlist, gtmp, level, cap);
        node_epi<<<gridNcap, 128, 0, stream>>>(hs, hf, gtmp,
                                               Gs_bih, Gs_bhh, Gf_bih, Gf_bhh,
                                               gate, noff, nlist, level, cap);
    }

    writeout<<<(ND + 255) / 256, 256, 0, stream>>>(hs, hf, d_out, ND);
}

// Round 3
// 451.500 us; speedup vs baseline: 2.0037x; 1.1157x over previous
//
#include <hip/hip_runtime.h>
#include <hip/hip_bf16.h>

typedef __hip_bfloat16 bf16;

#define D 128
#define NLEV 5
#define TE 8   // edges per tile
#define TN 8   // nodes per tile

// gate code -> t (enumerate index in CODES=[3,2,5,1,4]); index 0 unused
__constant__ int TMAP[6] = { -1, 3, 1, 0, 4, 2 };
// gate code -> func-aggregator index (FIDX={3:0,5:1,1:2,4:3}); codes 0,2 unused
__constant__ int FMAP[6] = { -1, 2, -1, 0, 3, 1 };

// dtype flag: 1 = float tensors stored as bf16, 0 = stored as float32
__device__ int g_flag;

__device__ __forceinline__ float sigm(float x) { return 1.0f / (1.0f + __expf(-x)); }

template <int ISB>
__device__ __forceinline__ float ld(const void* p, size_t i) {
    if (ISB) return __bfloat162float(((const bf16*)p)[i]);
    return ((const float*)p)[i];
}

// load two adjacent elements (i must be even)
template <int ISB>
__device__ __forceinline__ float2 ld2(const void* p, size_t i) {
    if (ISB) {
        __hip_bfloat162 v = *(const __hip_bfloat162*)((const bf16*)p + i);
        return make_float2(__bfloat162float(v.x), __bfloat162float(v.y));
    }
    return *(const float2*)((const float*)p + i);
}

// ---- dtype sniffer ----
__global__ void detect_dtype(const void* hs_init) {
    int t = threadIdx.x;
    float x = __bfloat162float(((const bf16*)hs_init)[2 * t]);
    float ax = fabsf(x);
    bool sane = (x == 0.0f) || (ax > 1e-4f && ax < 64.0f);
    unsigned long long m = __ballot(sane);
    if (t == 0) g_flag = (__popcll(m) >= 32) ? 1 : 0;
}

// ---- init: hs = PI ? hs_init : 0 ; hf = 0 ----
__global__ void init_state(const void* __restrict__ hs_init,
                           const int* __restrict__ gate,
                           float* __restrict__ hs, float* __restrict__ hf) {
    int v = blockIdx.x;
    int j = threadIdx.x;
    float val = 0.0f;
    if (gate[v] == 0) {
        size_t idx = (size_t)v * D + j;
        val = g_flag ? ld<1>(hs_init, idx) : ld<0>(hs_init, idx);
    }
    hs[(size_t)v * D + j] = val;
    hf[(size_t)v * D + j] = 0.0f;
}

// ================= bucketing: (level-1)*5 + t, levels 1..4 =================
__global__ void count_bins(const int* __restrict__ dstA, const int* __restrict__ gate,
                           const int* __restrict__ lev, int E, int N,
                           int* __restrict__ ecnt, int* __restrict__ ncnt) {
    __shared__ int lc[40];
    int tid = threadIdx.x;
    if (tid < 40) lc[tid] = 0;
    __syncthreads();
    int i = blockIdx.x * blockDim.x + tid;
    if (i < E) {
        int d = dstA[i]; int l = lev[d];
        if (l >= 1 && l < NLEV) atomicAdd(&lc[(l - 1) * 5 + TMAP[gate[d]]], 1);
    }
    if (i < N) {
        int l = lev[i];
        if (l >= 1 && l < NLEV && gate[i] >= 1) atomicAdd(&lc[20 + (l - 1) * 5 + TMAP[gate[i]]], 1);
    }
    __syncthreads();
    if (tid < 20 && lc[tid]) atomicAdd(&ecnt[tid], lc[tid]);
    if (tid >= 20 && tid < 40 && lc[tid]) atomicAdd(&ncnt[tid - 20], lc[tid]);
}

__global__ void scan_offsets(const int* __restrict__ ecnt, const int* __restrict__ ncnt,
                             int* __restrict__ eoff, int* __restrict__ noff) {
    if (threadIdx.x == 0 && blockIdx.x == 0) {
        int o = 0;
        for (int b = 0; b < 20; ++b) { eoff[b] = o; o += ((ecnt[b] + TE - 1) / TE) * TE; }
        eoff[20] = o;
        o = 0;
        for (int b = 0; b < 20; ++b) { noff[b] = o; o += ((ncnt[b] + TN - 1) / TN) * TN; }
        noff[20] = o;
    }
}

__global__ void fill_bins(const int* __restrict__ dstA, const int* __restrict__ gate,
                          const int* __restrict__ lev, int E, int N,
                          const int* __restrict__ eoff, const int* __restrict__ noff,
                          int* __restrict__ ecur, int* __restrict__ ncur,
                          int* __restrict__ elist, int* __restrict__ nlist) {
    __shared__ int ec[20], nc[20], eb[20], nb[20];
    int tid = threadIdx.x;
    if (tid < 20) { ec[tid] = 0; nc[tid] = 0; }
    __syncthreads();
    int i = blockIdx.x * blockDim.x + tid;
    int be = -1, re = 0, bn = -1, rn = 0;
    if (i < E) {
        int d = dstA[i]; int l = lev[d];
        if (l >= 1 && l < NLEV) { be = (l - 1) * 5 + TMAP[gate[d]]; re = atomicAdd(&ec[be], 1); }
    }
    if (i < N) {
        int l = lev[i];
        if (l >= 1 && l < NLEV && gate[i] >= 1) { bn = (l - 1) * 5 + TMAP[gate[i]]; rn = atomicAdd(&nc[bn], 1); }
    }
    __syncthreads();
    if (tid < 20) {
        eb[tid] = ec[tid] ? atomicAdd(&ecur[tid], ec[tid]) : 0;
        nb[tid] = nc[tid] ? atomicAdd(&ncur[tid], nc[tid]) : 0;
    }
    __syncthreads();
    if (be >= 0) elist[eoff[be] + eb[be] + re] = i;
    if (bn >= 0) nlist[noff[bn] + nb[bn] + rn] = i;
}

// ================= register-tiled R-row GEMM slice =================
// out[R][2] = X[R][K] @ W[K][cols] at cols (c0, c0+1), + optional bias.
// Adjacent-col trick: one float2/bf16x2 load yields both columns' weights.
template <int ISB, int K, int R>
__device__ __forceinline__ void mmT(
    const float* __restrict__ xs, int xstride,
    const void* __restrict__ W, size_t wofs, int wstride,
    const void* __restrict__ B, size_t bofs,
    int c0, float (&out)[R][2]) {
    float2 b = B ? ld2<ISB>(B, bofs + c0) : make_float2(0.f, 0.f);
#pragma unroll
    for (int r = 0; r < R; ++r) { out[r][0] = b.x; out[r][1] = b.y; }
#pragma unroll 2
    for (int i = 0; i < K; i += 4) {
        size_t w0 = wofs + (size_t)i * wstride + c0;
        float2 wa = ld2<ISB>(W, w0);
        float2 wb = ld2<ISB>(W, w0 + wstride);
        float2 wc = ld2<ISB>(W, w0 + 2 * (size_t)wstride);
        float2 wd = ld2<ISB>(W, w0 + 3 * (size_t)wstride);
#pragma unroll
        for (int r = 0; r < R; ++r) {
            const float4 xv = *reinterpret_cast<const float4*>(xs + r * xstride + i);
            out[r][0] = fmaf(xv.w, wd.x, fmaf(xv.z, wc.x, fmaf(xv.y, wb.x, fmaf(xv.x, wa.x, out[r][0]))));
            out[r][1] = fmaf(xv.w, wd.y, fmaf(xv.z, wc.y, fmaf(xv.y, wb.y, fmaf(xv.x, wa.y, out[r][1]))));
        }
    }
}

// ================= edge tiles: 2 waves/block: wave0=structural, wave1=functional =================
template <int ISB>
__device__ void edge_tiles_body(
    const float* __restrict__ hs, const float* __restrict__ hf,
    const void* __restrict__ Ws1, const void* __restrict__ bs1,
    const void* __restrict__ Ws2, const void* __restrict__ bs2,
    const void* __restrict__ Wf1, const void* __restrict__ bf1,
    const void* __restrict__ Wf2, const void* __restrict__ bf2,
    const void* __restrict__ Wnf1, const void* __restrict__ bnf1,
    const void* __restrict__ Wnf2, const void* __restrict__ bnf2,
    const int* __restrict__ srcA, const int* __restrict__ dstA,
    const int* __restrict__ gate,
    const int* __restrict__ eoff, const int* __restrict__ elist,
    float* __restrict__ agg_s, float* __restrict__ agg_f, int level,
    int* se, int* de, float (*x)[2 * D], float (*hid)[TE][D]) {
    int lo = eoff[(level - 1) * 5];
    int hi = eoff[(level - 1) * 5 + 5];
    int base = lo + blockIdx.x * TE;
    if (base >= hi) return;
    int tid = threadIdx.x;
    int wv = tid >> 6;        // 0: structural, 1: functional
    int l = tid & 63;
    int c0 = 2 * l;

    int e0 = elist[base];
    int c = gate[dstA[e0]];   // uniform over tile (buckets padded to TE)
    int t = TMAP[c];

    if (tid < TE) {
        int e = elist[base + tid];
        se[tid] = (e < 0) ? -1 : srcA[e];
        de[tid] = (e < 0) ? -1 : dstA[e];
    }
    __syncthreads();

    // cooperative gather: wave0 fills hs-half, wave1 fills hf-half
    const float* hsrc = wv ? hf : hs;
#pragma unroll
    for (int r = 0; r < TE; ++r) {
        int s = se[r];
        float2 v = make_float2(0.f, 0.f);
        if (s >= 0) v = *(const float2*)&hsrc[(size_t)s * D + c0];
        *(float2*)&x[r][wv * D + c0] = v;
    }
    __syncthreads();

    float acc[TE][2];

    // ---- layer 1 ----
    if (wv == 0) {
        mmT<ISB, 128, TE>(&x[0][0], 2 * D, Ws1, (size_t)t * D * D, D, bs1, (size_t)t * D, c0, acc);
    } else if (c == 2) {
        mmT<ISB, 128, TE>(&x[0][D], 2 * D, Wnf1, 0, D, bnf1, 0, c0, acc);
    } else {
        int fi = FMAP[c];
        mmT<ISB, 256, TE>(&x[0][0], 2 * D, Wf1, (size_t)fi * 2 * D * D, D, bf1, (size_t)fi * D, c0, acc);
    }
#pragma unroll
    for (int r = 0; r < TE; ++r) {
        hid[wv][r][c0] = fmaxf(acc[r][0], 0.f);
        hid[wv][r][c0 + 1] = fmaxf(acc[r][1], 0.f);
    }
    __syncthreads();

    // ---- layer 2 ----
    if (wv == 0) {
        mmT<ISB, 128, TE>(&hid[0][0][0], D, Ws2, (size_t)t * D * D, D, bs2, (size_t)t * D, c0, acc);
    } else if (c == 2) {
        mmT<ISB, 128, TE>(&hid[1][0][0], D, Wnf2, 0, D, bnf2, 0, c0, acc);
    } else {
        int fi = FMAP[c];
        mmT<ISB, 128, TE>(&hid[1][0][0], D, Wf2, (size_t)fi * D * D, D, bf2, (size_t)fi * D, c0, acc);
    }
    float* aggp = wv ? agg_f : agg_s;
#pragma unroll
    for (int r = 0; r < TE; ++r) {
        int d = de[r];
        if (d >= 0) {
            atomicAdd(&aggp[(size_t)d * D + c0], acc[r][0]);
            atomicAdd(&aggp[(size_t)d * D + c0 + 1], acc[r][1]);
        }
    }
}

__global__ __launch_bounds__(128) void edge_tiles(
    const float* hs, const float* hf,
    const void* Ws1, const void* bs1, const void* Ws2, const void* bs2,
    const void* Wf1, const void* bf1, const void* Wf2, const void* bf2,
    const void* Wnf1, const void* bnf1, const void* Wnf2, const void* bnf2,
    const int* srcA, const int* dstA, const int* gate,
    const int* eoff, const int* elist,
    float* agg_s, float* agg_f, int level) {
    __shared__ int se[TE], de[TE];
    __shared__ __align__(16) float x[TE][2 * D];
    __shared__ __align__(16) float hid[2][TE][D];
    if (g_flag)
        edge_tiles_body<1>(hs, hf, Ws1, bs1, Ws2, bs2, Wf1, bf1, Wf2, bf2,
                           Wnf1, bnf1, Wnf2, bnf2, srcA, dstA, gate, eoff, elist,
                           agg_s, agg_f, level, se, de, x, hid);
    else
        edge_tiles_body<0>(hs, hf, Ws1, bs1, Ws2, bs2, Wf1, bf1, Wf2, bf2,
                           Wnf1, bnf1, Wnf2, bnf2, srcA, dstA, gate, eoff, elist,
                           agg_s, agg_f, level, se, de, x, hid);
}

// ================= node GEMM: gi partials, split (pass, colgroup, k-half) =================
// blockIdx.y = p*6 + g*2 + h :  p in {hs,hf}, g in {r,z,n}, h = K-half
template <int ISB>
__device__ void node_gemm_body(
    const float* __restrict__ agg_s, const float* __restrict__ agg_f,
    const void* __restrict__ Gs_wih, const void* __restrict__ Gf_wih,
    const int* __restrict__ gate,
    const int* __restrict__ noff, const int* __restrict__ nlist,
    float* __restrict__ gtmp, int level, int cap,
    int* nd, float (*x)[64]) {
    int lo = noff[(level - 1) * 5];
    int hi = noff[(level - 1) * 5 + 5];
    int base = lo + blockIdx.x * TN;
    if (base >= hi) return;
    int y = blockIdx.y;
    int p = y / 6, gh = y % 6;
    int g = gh / 2, h = gh % 2;
    int l = threadIdx.x;
    int c0 = 2 * l;
    int t = TMAP[gate[nlist[base]]];

    const float* agg = p ? agg_f : agg_s;
    const void* wih = p ? Gf_wih : Gs_wih;

    if (l < TN) nd[l] = nlist[base + l];
    __syncthreads();
#pragma unroll
    for (int r = 0; r < TN; ++r) {
        int v = nd[r];
        x[r][l] = (v >= 0) ? agg[(size_t)v * D + h * 64 + l] : 0.f;
    }
    __syncthreads();

    float acc[TN][2];
    size_t wofs = (size_t)t * D * 3 * D + (size_t)(h * 64) * 3 * D;
    mmT<ISB, 64, TN>(&x[0][0], 64, wih, wofs, 3 * D, (const void*)0, 0, g * 128 + c0, acc);

    size_t tb = (((size_t)(p * 2 + h)) * cap + (base - lo)) * 384 + g * 128 + c0;
#pragma unroll
    for (int r = 0; r < TN; ++r) {
        *(float2*)&gtmp[tb + (size_t)r * 384] = make_float2(acc[r][0], acc[r][1]);
    }
}

__global__ __launch_bounds__(64) void node_gemm(
    const float* agg_s, const float* agg_f,
    const void* Gs_wih, const void* Gf_wih,
    const int* gate, const int* noff, const int* nlist,
    float* gtmp, int level, int cap) {
    __shared__ int nd[TN];
    __shared__ __align__(16) float x[TN][64];
    if (g_flag)
        node_gemm_body<1>(agg_s, agg_f, Gs_wih, Gf_wih, gate, noff, nlist, gtmp, level, cap, nd, x);
    else
        node_gemm_body<0>(agg_s, agg_f, Gs_wih, Gf_wih, gate, noff, nlist, gtmp, level, cap, nd, x);
}

// ================= node epilogue: sum K-halves + biases + GRU nonlinearity =================
template <int ISB>
__device__ void node_epi_body(
    float* __restrict__ hs, float* __restrict__ hf,
    const float* __restrict__ gtmp,
    const void* __restrict__ Gs_bih, const void* __restrict__ Gs_bhh,
    const void* __restrict__ Gf_bih, const void* __restrict__ Gf_bhh,
    const int* __restrict__ gate,
    const int* __restrict__ noff, const int* __restrict__ nlist,
    int level, int cap) {
    int lo = noff[(level - 1) * 5];
    int hi = noff[(level - 1) * 5 + 5];
    int base = lo + blockIdx.x * TN;
    if (base >= hi) return;
    int j = threadIdx.x;  // 0..127
    int t = TMAP[gate[nlist[base]]];

#pragma unroll
    for (int p = 0; p < 2; ++p) {
        const void* bih = p ? Gf_bih : Gs_bih;
        const void* bhh = p ? Gf_bhh : Gs_bhh;
        float br = ld<ISB>(bih, (size_t)t * 384 + j);
        float bz = ld<ISB>(bih, (size_t)t * 384 + 128 + j);
        float bn = ld<ISB>(bih, (size_t)t * 384 + 256 + j);
        float hr = ld<ISB>(bhh, (size_t)t * 384 + j);
        float hz = ld<ISB>(bhh, (size_t)t * 384 + 128 + j);
        float hn = ld<ISB>(bhh, (size_t)t * 384 + 256 + j);
        float* hout = p ? hf : hs;
        const float* g0 = gtmp + ((size_t)(p * 2 + 0)) * cap * 384;
        const float* g1 = gtmp + ((size_t)(p * 2 + 1)) * cap * 384;
#pragma unroll
        for (int r = 0; r < TN; ++r) {
            int v = nlist[base + r];
            if (v < 0) continue;
            size_t pos = (size_t)(base - lo + r) * 384;
            float gr = g0[pos + j] + g1[pos + j];
            float gz = g0[pos + 128 + j] + g1[pos + 128 + j];
            float gn = g0[pos + 256 + j] + g1[pos + 256 + j];
            float rr = sigm(gr + br + hr);
            float z = sigm(gz + bz + hz);
            float n = tanhf(gn + bn + rr * hn);
            hout[(size_t)v * D + j] = (1.f - z) * n;
        }
    }
}

__global__ __launch_bounds__(128) void node_epi(
    float* hs, float* hf, const float* gtmp,
    const void* Gs_bih, const void* Gs_bhh,
    const void* Gf_bih, const void* Gf_bhh,
    const int* gate, const int* noff, const int* nlist, int level, int cap) {
    if (g_flag)
        node_epi_body<1>(hs, hf, gtmp, Gs_bih, Gs_bhh, Gf_bih, Gf_bhh,
                         gate, noff, nlist, level, cap);
    else
        node_epi_body<0>(hs, hf, gtmp, Gs_bih, Gs_bhh, Gf_bih, Gf_bhh,
                         gate, noff, nlist, level, cap);
}

// ---------------- writeout ----------------
__global__ void writeout(const float* __restrict__ hs, const float* __restrict__ hf,
                         void* __restrict__ out, int ND) {
    int i = blockIdx.x * blockDim.x + threadIdx.x;
    if (i >= ND) return;
    if (g_flag) {
        ((bf16*)out)[i] = __float2bfloat16(hs[i]);
        ((bf16*)out)[ND + i] = __float2bfloat16(hf[i]);
    } else {
        ((float*)out)[i] = hs[i];
        ((float*)out)[ND + i] = hf[i];
    }
}

extern "C" void kernel_launch(void* const* d_in, const int* in_sizes, int n_in,
                              void* d_out, int out_size, void* d_ws, size_t ws_size,
                              hipStream_t stream) {
    const void* hs_init = d_in[0];
    const void* Ws1 = d_in[1];
    const void* bs1 = d_in[2];
    const void* Ws2 = d_in[3];
    const void* bs2 = d_in[4];
    const void* Wf1 = d_in[5];
    const void* bf1 = d_in[6];
    const void* Wf2 = d_in[7];
    const void* bf2 = d_in[8];
    const void* Wnf1 = d_in[9];
    const void* bnf1 = d_in[10];
    const void* Wnf2 = d_in[11];
    const void* bnf2 = d_in[12];
    const void* Gs_wih = d_in[13];
    // d_in[14] = Gs_whh (unused: h==0 at GRU time)
    const void* Gs_bih = d_in[15];
    const void* Gs_bhh = d_in[16];
    const void* Gf_wih = d_in[17];
    // d_in[18] = Gf_whh (unused)
    const void* Gf_bih = d_in[19];
    const void* Gf_bhh = d_in[20];
    const int* edge_index = (const int*)d_in[21];
    const int* gate = (const int*)d_in[22];
    const int* lev = (const int*)d_in[23];

    int E = in_sizes[21] / 2;
    int N = in_sizes[22];
    int ND = N * D;
    // per-level node window bound: levels are ~N/NLEV nodes + bucket padding
    int cap = ((N / NLEV + 5 * TN + 64) + TN - 1) / TN * TN;

    float* hs = (float*)d_ws;
    float* hf = hs + ND;
    float* agg_s = hf + ND;
    float* agg_f = agg_s + ND;
    float* gtmp = agg_f + ND;                  // 4 * cap * 384 floats
    int* meta = (int*)(gtmp + (size_t)4 * cap * 384);
    int* ecnt = meta;           // 20
    int* ncnt = ecnt + 20;      // 20
    int* ecur = ncnt + 20;      // 20
    int* ncur = ecur + 20;      // 20
    int* eoff = ncur + 20;      // 21
    int* noff = eoff + 21;      // 21
    int* elist = noff + 21;     // E + 20*TE
    int* nlist = elist + (E + 20 * TE);  // N + 20*TN

    const int* srcA = edge_index;
    const int* dstA = edge_index + E;

    detect_dtype<<<1, 64, 0, stream>>>(hs_init);
    hipMemsetAsync(agg_s, 0, (size_t)2 * ND * sizeof(float), stream);
    hipMemsetAsync(meta, 0, 80 * sizeof(int), stream);
    hipMemsetAsync(elist, 0xFF, (size_t)(E + 20 * TE + N + 20 * TN) * sizeof(int), stream);
    init_state<<<N, D, 0, stream>>>(hs_init, gate, hs, hf);

    int mx = (E > N) ? E : N;
    count_bins<<<(mx + 255) / 256, 256, 0, stream>>>(dstA, gate, lev, E, N, ecnt, ncnt);
    scan_offsets<<<1, 64, 0, stream>>>(ecnt, ncnt, eoff, noff);
    fill_bins<<<(mx + 255) / 256, 256, 0, stream>>>(dstA, gate, lev, E, N,
                                                    eoff, noff, ecur, ncur, elist, nlist);

    int gridE = (E + 20 * TE) / TE + 1;
    int gridNcap = cap / TN;
    for (int level = 1; level < NLEV; ++level) {
        edge_tiles<<<gridE, 128, 0, stream>>>(hs, hf, Ws1, bs1, Ws2, bs2,
                                              Wf1, bf1, Wf2, bf2,
                                              Wnf1, bnf1, Wnf2, bnf2,
                                              srcA, dstA, gate, eoff, elist,
                                              agg_s, agg_f, level);
        node_gemm<<<dim3(gridNcap, 12), 64, 0, stream>>>(agg_s, agg_f, Gs_wih, Gf_wih,
                                                         gate, noff, nlist, gtmp, level, cap);
        node_epi<<<gridNcap, 128, 0, stream>>>(hs, hf, gtmp,
                                               Gs_bih, Gs_bhh, Gf_bih, Gf_bhh,
                                               gate, noff, nlist, level, cap);
    }

    writeout<<<(ND + 255) / 256, 256, 0, stream>>>(hs, hf, d_out, ND);
}